// Round 1
// baseline (87.802 us; speedup 1.0000x reference)
//
#include <hip/hip_runtime.h>

#define NB 4
#define SS 256
#define DM 128
#define NH 8
#define HD 16
#define DDim 64
#define TT 257

// workspace offsets (in floats)
#define OFF_WQE 0        // 8*128
#define OFF_WKE 1024     // 8*128
#define OFF_BQE 2048     // 8
#define OFF_BKE 2056     // 8
#define OFF_SQ  2064     // B*H*T = 8224
#define OFF_SK  10288    // 8224
#define OFF_G   18512    // B*4*T = 4112
#define OFF_V   22624    // B*H*T*HD = 131584
// total 154208 floats = 616832 bytes

#define ATT_BASE (NB*TT*NH*HD)   // 131584

// ---------------- Kernel A: fold aw into Wq/Wk ----------------
__global__ __launch_bounds__(256) void eff_kernel(
    const float* __restrict__ Wq, const float* __restrict__ bq,
    const float* __restrict__ Wk, const float* __restrict__ bk,
    const float* __restrict__ aw, float* __restrict__ ws)
{
  int tid = threadIdx.x;
  for (int o = tid; o < 1024; o += 256) {
    int h = o >> 7, e = o & 127;
    float sq_ = 0.f, sk_ = 0.f;
    for (int d = 0; d < 16; ++d) {
      sq_ += Wq[(h*16+d)*DM + e] * aw[d];
      sk_ += Wk[(h*16+d)*DM + e] * aw[16+d];
    }
    ws[OFF_WQE + o] = sq_;
    ws[OFF_WKE + o] = sk_;
  }
  if (tid < 8) {
    float s = 0.f;
    for (int d = 0; d < 16; ++d) s += bq[tid*16+d] * aw[d];
    ws[OFF_BQE + tid] = s;
  } else if (tid < 16) {
    int h = tid - 8;
    float s = 0.f;
    for (int d = 0; d < 16; ++d) s += bk[h*16+d] * aw[16+d];
    ws[OFF_BKE + h] = s;
  }
}

// ---------------- Kernel B: per-position projections ----------------
// grid 514 blocks x 256 threads; block handles 2 positions.
// thread = (p, c): p = tid>>7 (position in pair), c = tid&127 (channel)
__global__ __launch_bounds__(256) void proj_kernel(
    const float* __restrict__ de, const float* __restrict__ nve,
    const float* __restrict__ Wv, const float* __restrict__ bv,
    const float* __restrict__ aw, float* __restrict__ ws)
{
  __shared__ float xs[2][DM];
  int tid = threadIdx.x;
  int p = tid >> 7, c = tid & 127;
  int pos = blockIdx.x * 2 + p;
  int b = pos / TT, t = pos % TT;

  xs[p][c] = nve[pos * DM + c];
  __syncthreads();

  float accv = bv[c];
  float acce = 0.f;
  const float* we = ws;  // overwritten below when used
  if (c < 8)       { acce = ws[OFF_BQE + c];     we = ws + OFF_WQE + c*128; }
  else if (c < 16) { acce = ws[OFF_BKE + (c-8)]; we = ws + OFF_WKE + (c-8)*128; }
  const float* wvrow = Wv + c * DM;

  for (int e = 0; e < DM; ++e) {
    float x = xs[p][e];
    accv += x * wvrow[e];
    if (c < 16) acce += x * we[e];
  }

  int h = c >> 4, d = c & 15;
  ws[OFF_V + ((b*NH + h)*TT + t)*HD + d] = accv;
  if (c < 8)       ws[OFF_SQ + (b*NH + c)*TT + t]     = acce;
  else if (c < 16) ws[OFF_SK + (b*NH + (c-8))*TT + t] = acce;

  // G[b,m,t] = dot(de[b,t-1, 16m:16m+16], ae);  G[.,.,0] = 0
  if (c >= 64) {
    int m = (c - 64) >> 4, gd = c & 15;
    float val = 0.f;
    if (t > 0) val = de[(b*SS + (t-1))*DDim + m*16 + gd] * aw[32 + gd];
    val += __shfl_xor(val, 1);
    val += __shfl_xor(val, 2);
    val += __shfl_xor(val, 4);
    val += __shfl_xor(val, 8);
    if (gd == 0) ws[OFF_G + (b*4 + m)*TT + t] = val;
  }
}

// ---------------- Kernel C: attention rows ----------------
// grid = B*H*ceil(T/8) = 1056 blocks x 256 threads; each block: 8 rows of one (b,h)
__global__ __launch_bounds__(256) void attn_kernel(
    const float* __restrict__ ws, const float* __restrict__ ab_ptr,
    float* __restrict__ out)
{
  __shared__ float u_lds[TT];
  __shared__ float p_lds[TT];
  __shared__ float rbuf[4], sbuf[4], wbuf[64];

  int tid  = threadIdx.x;
  int wave = tid >> 6, lane = tid & 63;
  int rb = blockIdx.x % 33;
  int bh = blockIdx.x / 33;
  int h = bh & 7, b = bh >> 3;
  int i0 = rb * 8;
  float ab = ab_ptr[0];

  const float* skp   = ws + OFF_SK + bh*TT;
  const float* gp_lo = ws + OFF_G + (b*4 + (h & 3))*TT;  // G[b, h mod 4, :]

  // row-invariant column vector u[j] = sk[j] + (h>=4 ? G[b,h-4,j] : 0)
  for (int j = tid; j < TT; j += 256) {
    float u = skp[j];
    if (h >= 4) u += gp_lo[j];
    u_lds[j] = u;
  }
  __syncthreads();

  for (int r = 0; r < 8; ++r) {
    int i = i0 + r;
    if (i >= TT) break;

    float Ci = ws[OFF_SQ + bh*TT + i] + ab;
    if (i > 0 && h < 4) Ci += gp_lo[i];           // E1 row term
    bool ext = (i == 0 && h < 4);                 // CLS row extra G for low heads

    int  j0 = tid;
    bool m0 = (j0 == 0) || (i > 0 && j0 == i);
    float l0 = Ci + u_lds[j0] + (ext ? gp_lo[j0] : 0.f);
    float lm = m0 ? -3.0e38f : l0;
    float l1 = 0.f; bool m1 = true;
    if (tid == 0) {
      m1 = (i == 256);
      l1 = Ci + u_lds[256] + (ext ? gp_lo[256] : 0.f);
      if (!m1) lm = fmaxf(lm, l1);
    }
    #pragma unroll
    for (int off = 1; off < 64; off <<= 1) lm = fmaxf(lm, __shfl_xor(lm, off));
    if (lane == 0) rbuf[wave] = lm;
    __syncthreads();
    float M = fmaxf(fmaxf(rbuf[0], rbuf[1]), fmaxf(rbuf[2], rbuf[3]));

    float p0 = m0 ? 0.f : expf(l0 - M);
    float p1 = (tid == 0 && !m1) ? expf(l1 - M) : 0.f;
    float ls = p0 + p1;
    #pragma unroll
    for (int off = 1; off < 64; off <<= 1) ls += __shfl_xor(ls, off);
    if (lane == 0) sbuf[wave] = ls;
    __syncthreads();
    float inv = 1.0f / (sbuf[0] + sbuf[1] + sbuf[2] + sbuf[3]);

    float pn0 = p0 * inv;
    float* arow = out + ATT_BASE + (bh*TT + i)*TT;
    arow[j0] = pn0;
    p_lds[j0] = pn0;
    if (tid == 0) { float pn1 = p1 * inv; arow[256] = pn1; p_lds[256] = pn1; }
    __syncthreads();

    // ctx[d] = sum_j p[j] * v[b,h,j,d]
    int g = tid >> 4, dd = tid & 15;
    float acc = 0.f;
    const float* vb = ws + OFF_V + bh*TT*HD + dd;
    for (int jj = g; jj < TT; jj += 16)
      acc += p_lds[jj] * vb[jj*HD];
    acc += __shfl_xor(acc, 16);
    acc += __shfl_xor(acc, 32);
    if (lane < 16) wbuf[wave*16 + lane] = acc;
    __syncthreads();
    if (tid < 16) {
      float o = wbuf[tid] + wbuf[16+tid] + wbuf[32+tid] + wbuf[48+tid];
      out[((b*TT + i)*NH + h)*HD + tid] = o;
    }
  }
}

extern "C" void kernel_launch(void* const* d_in, const int* in_sizes, int n_in,
                              void* d_out, int out_size, void* d_ws, size_t ws_size,
                              hipStream_t stream) {
  const float* de  = (const float*)d_in[0];
  const float* nve = (const float*)d_in[1];
  const float* Wq  = (const float*)d_in[2];
  const float* bq  = (const float*)d_in[3];
  const float* Wk  = (const float*)d_in[4];
  const float* bk  = (const float*)d_in[5];
  const float* Wv  = (const float*)d_in[6];
  const float* bv  = (const float*)d_in[7];
  const float* aw  = (const float*)d_in[8];
  const float* ab  = (const float*)d_in[9];
  float* out = (float*)d_out;
  float* ws  = (float*)d_ws;

  eff_kernel<<<1, 256, 0, stream>>>(Wq, bq, Wk, bk, aw, ws);
  proj_kernel<<<(NB*TT + 1)/2, 256, 0, stream>>>(de, nve, Wv, bv, aw, ws);
  attn_kernel<<<NB*NH*((TT + 7)/8), 256, 0, stream>>>(ws, ab, out);
}

// Round 2
// 35.272 us; speedup vs baseline: 2.4893x; 2.4893x over previous
//
#include <hip/hip_runtime.h>

#define NB 4
#define SS 256
#define DM 128
#define NH 8
#define HD 16
#define DDim 64
#define TT 257
#define NPOS (NB*TT)   // 1028

// workspace float offsets
#define OFF_WQE 0        // 8*128
#define OFF_WKE 1024     // 8*128
#define OFF_BQE 2048     // 8 (padded)
#define OFF_BKE 2064     // 8 (padded)
#define OFF_SQ  2080     // 32*257 = 8224
#define OFF_SK  10304    // 8224
#define OFF_G   18528    // 16*257 = 4112
#define OFF_V   22640    // 32*257*16 = 131584
// total 154224 floats = 616896 bytes

#define ATT_BASE (NB*TT*NH*HD)   // 131584

// ---------------- Kernel A: setup (eff weights + G table) ----------------
// grid 8 blocks x 256. bid 0-3: eff weights; bid 4-7: G table.
__global__ __launch_bounds__(256) void setup_kernel(
    const float* __restrict__ de,
    const float* __restrict__ Wq, const float* __restrict__ bq,
    const float* __restrict__ Wk, const float* __restrict__ bk,
    const float* __restrict__ aw, float* __restrict__ ws)
{
  int tid = threadIdx.x, bid = blockIdx.x;
  if (bid < 4) {
    int idx = bid*256 + tid;       // 0..1023
    int h = idx >> 7, e = idx & 127;
    float sq_ = 0.f, sk_ = 0.f;
    #pragma unroll
    for (int d = 0; d < 16; ++d) {
      sq_ += Wq[(h*16+d)*DM + e] * aw[d];
      sk_ += Wk[(h*16+d)*DM + e] * aw[16+d];
    }
    ws[OFF_WQE + idx] = sq_;
    ws[OFF_WKE + idx] = sk_;
    if (bid == 0 && tid < 16) {
      int hh = tid & 7; bool isq = (tid < 8);
      float s = 0.f;
      #pragma unroll
      for (int d = 0; d < 16; ++d)
        s += isq ? bq[hh*16+d]*aw[d] : bk[hh*16+d]*aw[16+d];
      ws[(isq ? OFF_BQE : OFF_BKE) + hh] = s;
    }
  } else {
    // G[bm][t], bm = b*4+m, 16*257 = 4112 entries, 1028 per block
    int chunk = (bid - 4) * 1028;
    int lim = chunk + 1028;
    for (int r = 0; r < 5; ++r) {
      int gi = chunk + tid + r*256;
      if (gi < lim && gi < 16*TT) {
        int bm = gi / TT, t = gi - bm*TT;
        float val = 0.f;
        if (t > 0) {
          int b = bm >> 2, m = bm & 3;
          const float* dp = de + (b*SS + (t-1))*DDim + m*16;
          #pragma unroll
          for (int d = 0; d < 16; ++d) val += dp[d] * aw[32+d];
        }
        ws[OFF_G + gi] = val;
      }
    }
  }
}

// ---------------- Kernel B: projections (V + sq + sk) ----------------
// grid 65 blocks x 256; block = 16 positions. thread (ph=tid>>7 -> 8 pos, c=tid&127)
__global__ __launch_bounds__(256) void proj_kernel(
    const float* __restrict__ nve,
    const float* __restrict__ Wv, const float* __restrict__ bv,
    float* __restrict__ ws)
{
  __shared__ float4 xs4[16][32];
  int tid = threadIdx.x;
  int pos0 = blockIdx.x * 16;
  const float4* nve4 = (const float4*)nve;
  for (int idx = tid; idx < 512; idx += 256) {
    int lp = idx >> 5, e4 = idx & 31;
    int pos = pos0 + lp;
    xs4[lp][e4] = (pos < NPOS) ? nve4[pos*32 + e4] : make_float4(0.f,0.f,0.f,0.f);
  }
  __syncthreads();

  int c = tid & 127, ph = tid >> 7;
  const float4* wv4 = (const float4*)(Wv + c*DM);
  bool doe = (c < 16);
  const float4* we4 = doe
      ? (const float4*)(ws + (c < 8 ? OFF_WQE + c*DM : OFF_WKE + (c-8)*DM))
      : wv4;

  float acc[8]  = {0.f,0.f,0.f,0.f,0.f,0.f,0.f,0.f};
  float acce[8] = {0.f,0.f,0.f,0.f,0.f,0.f,0.f,0.f};

  #pragma unroll 4
  for (int e4 = 0; e4 < 32; ++e4) {
    float4 w = wv4[e4];
    #pragma unroll
    for (int p = 0; p < 8; ++p) {
      float4 x = xs4[ph*8+p][e4];
      acc[p] += w.x*x.x + w.y*x.y + w.z*x.z + w.w*x.w;
    }
    if (doe) {
      float4 we = we4[e4];
      #pragma unroll
      for (int p = 0; p < 8; ++p) {
        float4 x = xs4[ph*8+p][e4];
        acce[p] += we.x*x.x + we.y*x.y + we.z*x.z + we.w*x.w;
      }
    }
  }

  int h = c >> 4, d = c & 15;
  float bvc = bv[c];
  float be  = doe ? ws[(c < 8 ? OFF_BQE + c : OFF_BKE + (c-8))] : 0.f;
  for (int p = 0; p < 8; ++p) {
    int pos = pos0 + ph*8 + p;
    if (pos >= NPOS) break;
    int b = pos / TT, t = pos - b*TT;
    ws[OFF_V + ((b*NH + h)*TT + t)*HD + d] = acc[p] + bvc;
    if (c < 8)       ws[OFF_SQ + (b*NH + c)*TT + t]     = acce[p] + be;
    else if (c < 16) ws[OFF_SK + (b*NH + (c-8))*TT + t] = acce[p] + be;
  }
}

// ---------------- Kernel C: attention, one wave per row ----------------
// grid = 32 bh * 65 rowblocks = 2080 blocks x 256 (4 waves = 4 rows)
__global__ __launch_bounds__(256) void attn_kernel(
    const float* __restrict__ ws, const float* __restrict__ ab_ptr,
    float* __restrict__ out)
{
  __shared__ float p_lds[4][TT+3];
  int tid  = threadIdx.x;
  int wave = tid >> 6, lane = tid & 63;
  int rb = blockIdx.x % 65;
  int bh = blockIdx.x / 65;
  int h = bh & 7, b = bh >> 3;
  int i = rb*4 + wave;
  if (i >= TT) return;

  float ab = ab_ptr[0];
  const float* skp = ws + OFF_SK + bh*TT;
  const float* gp  = ws + OFF_G + (b*4 + (h & 3))*TT;
  const float* vws = ws + OFF_V + bh*TT*HD;

  float Ci = ws[OFF_SQ + bh*TT + i] + ab;
  if (i > 0 && h < 4) Ci += gp[i];                 // row edge term, low heads
  bool colg = (h >= 4) || (i == 0);                // column edge term applies

  float l[4];
  float lm = -3.0e38f;
  #pragma unroll
  for (int k = 0; k < 4; ++k) {
    int j = lane + 64*k;
    float u = skp[j] + (colg ? gp[j] : 0.f);
    l[k] = Ci + u;
    bool msk = (j == 0) || (i > 0 && j == i);
    if (!msk) lm = fmaxf(lm, l[k]);
  }
  float l4 = 0.f; bool has4 = false;
  if (lane == 0) {
    l4 = Ci + skp[256] + (colg ? gp[256] : 0.f);
    if (i != 256) { lm = fmaxf(lm, l4); has4 = true; }
  }
  #pragma unroll
  for (int off = 1; off < 64; off <<= 1) lm = fmaxf(lm, __shfl_xor(lm, off));

  float p[4], ps = 0.f;
  #pragma unroll
  for (int k = 0; k < 4; ++k) {
    int j = lane + 64*k;
    bool msk = (j == 0) || (i > 0 && j == i);
    p[k] = msk ? 0.f : expf(l[k] - lm);
    ps += p[k];
  }
  float p4 = has4 ? expf(l4 - lm) : 0.f;
  ps += p4;
  #pragma unroll
  for (int off = 1; off < 64; off <<= 1) ps += __shfl_xor(ps, off);
  float inv = 1.0f / ps;

  float* arow = out + ATT_BASE + (bh*TT + i)*TT;
  #pragma unroll
  for (int k = 0; k < 4; ++k) {
    float v = p[k] * inv;
    arow[lane + 64*k] = v;
    p_lds[wave][lane + 64*k] = v;
  }
  if (lane == 0) { float v = p4 * inv; arow[256] = v; p_lds[wave][256] = v; }

  // ctx[d] = sum_j p[j]*v[j,d]; same-wave LDS, no barrier needed
  int g = lane >> 4, d = lane & 15;
  float acc = 0.f;
  #pragma unroll 4
  for (int jj = g; jj < TT; jj += 4)
    acc += p_lds[wave][jj] * vws[jj*HD + d];
  acc += __shfl_xor(acc, 16);
  acc += __shfl_xor(acc, 32);
  if (lane < 16)
    out[((b*TT + i)*NH + h)*HD + lane] = acc;
}

extern "C" void kernel_launch(void* const* d_in, const int* in_sizes, int n_in,
                              void* d_out, int out_size, void* d_ws, size_t ws_size,
                              hipStream_t stream) {
  const float* de  = (const float*)d_in[0];
  const float* nve = (const float*)d_in[1];
  const float* Wq  = (const float*)d_in[2];
  const float* bq  = (const float*)d_in[3];
  const float* Wk  = (const float*)d_in[4];
  const float* bk  = (const float*)d_in[5];
  const float* Wv  = (const float*)d_in[6];
  const float* bv  = (const float*)d_in[7];
  const float* aw  = (const float*)d_in[8];
  const float* ab  = (const float*)d_in[9];
  float* out = (float*)d_out;
  float* ws  = (float*)d_ws;

  setup_kernel<<<8, 256, 0, stream>>>(de, Wq, bq, Wk, bk, aw, ws);
  proj_kernel<<<(NPOS + 15)/16, 256, 0, stream>>>(nve, Wv, bv, ws);
  attn_kernel<<<32*65, 256, 0, stream>>>(ws, ab, out);
}